// Round 1
// baseline (1976.891 us; speedup 1.0000x reference)
//
#include <hip/hip_runtime.h>

// 1-NN: for each query x_i (8192 x 128 f32), argmin_j over train_pts (32768 x 128 f32)
// of squared distance; output train_label[argmin]. argmin(x2+y2-2xy) == argmin(0.5*y2 - xy).

#define NQ 8192
#define NM 32768
#define ND 128
#define QT 16    // queries per block
#define BT 256   // threads per block

// Precompute h[j] = 0.5 * ||y_j||^2 into workspace.
__global__ void h_kernel(const float* __restrict__ y, float* __restrict__ h) {
  int j = blockIdx.x * blockDim.x + threadIdx.x;
  if (j >= NM) return;
  const float4* __restrict__ yp = (const float4*)(y + (size_t)j * ND);
  float s = 0.f;
#pragma unroll
  for (int u = 0; u < ND / 4; ++u) {
    float4 v = yp[u];
    s = fmaf(v.x, v.x, s);
    s = fmaf(v.y, v.y, s);
    s = fmaf(v.z, v.z, s);
    s = fmaf(v.w, v.w, s);
  }
  h[j] = 0.5f * s;
}

template <int USE_H>
__global__ __launch_bounds__(BT, 2) void nn_kernel(
    const float* __restrict__ x, const float* __restrict__ y,
    const float* __restrict__ lab, const float* __restrict__ h,
    float* __restrict__ out) {
  __shared__ float xs[QT][ND];
  const int t = threadIdx.x;
  const int q0 = blockIdx.x * QT;

  // Stage this block's 16 query rows into LDS (read later as uniform broadcasts).
  for (int i = t; i < QT * ND; i += BT) {
    xs[i / ND][i % ND] = x[(size_t)q0 * ND + i];
  }
  __syncthreads();

  float bv[QT];
  int bi[QT];
#pragma unroll
  for (int q = 0; q < QT; ++q) { bv[q] = 3.4e38f; bi[q] = 0; }

  // Each iteration: this thread handles train rows j0 = it*512 + t and j1 = j0 + 256.
  for (int it = 0; it < NM / (2 * BT); ++it) {
    const int j0 = it * (2 * BT) + t;
    const int j1 = j0 + BT;
    const float4* __restrict__ yp0 = (const float4*)(y + (size_t)j0 * ND);
    const float4* __restrict__ yp1 = (const float4*)(y + (size_t)j1 * ND);
    float acc0[QT], acc1[QT];
#pragma unroll
    for (int q = 0; q < QT; ++q) { acc0[q] = 0.f; acc1[q] = 0.f; }
    float y20 = 0.f, y21 = 0.f;
#pragma unroll 1   // keep k-chunk loop rolled: bounds live y-registers to 2x32 floats
    for (int kc = 0; kc < ND / 32; ++kc) {
      float4 a0[8], a1[8];
#pragma unroll
      for (int u = 0; u < 8; ++u) {
        a0[u] = yp0[kc * 8 + u];
        a1[u] = yp1[kc * 8 + u];
      }
      if (USE_H == 0) {
#pragma unroll
        for (int u = 0; u < 8; ++u) {
          y20 = fmaf(a0[u].x, a0[u].x, y20);
          y20 = fmaf(a0[u].y, a0[u].y, y20);
          y20 = fmaf(a0[u].z, a0[u].z, y20);
          y20 = fmaf(a0[u].w, a0[u].w, y20);
          y21 = fmaf(a1[u].x, a1[u].x, y21);
          y21 = fmaf(a1[u].y, a1[u].y, y21);
          y21 = fmaf(a1[u].z, a1[u].z, y21);
          y21 = fmaf(a1[u].w, a1[u].w, y21);
        }
      }
#pragma unroll
      for (int q = 0; q < QT; ++q) {
        float s0 = acc0[q], s1 = acc1[q];
#pragma unroll
        for (int u = 0; u < 8; ++u) {
          // Uniform address across the wave -> LDS broadcast ds_read_b128, no conflicts.
          const float4 xv = *(const float4*)&xs[q][kc * 32 + u * 4];
          s0 = fmaf(a0[u].x, xv.x, s0);
          s0 = fmaf(a0[u].y, xv.y, s0);
          s0 = fmaf(a0[u].z, xv.z, s0);
          s0 = fmaf(a0[u].w, xv.w, s0);
          s1 = fmaf(a1[u].x, xv.x, s1);
          s1 = fmaf(a1[u].y, xv.y, s1);
          s1 = fmaf(a1[u].z, xv.z, s1);
          s1 = fmaf(a1[u].w, xv.w, s1);
        }
        acc0[q] = s0;
        acc1[q] = s1;
      }
    }
    float h0, h1;
    if (USE_H) {
      h0 = h[j0];
      h1 = h[j1];
    } else {
      h0 = 0.5f * y20;
      h1 = 0.5f * y21;
    }
#pragma unroll
    for (int q = 0; q < QT; ++q) {
      const float s0 = h0 - acc0[q];
      const float s1 = h1 - acc1[q];
      // strict < keeps earliest index (j0 < j1, and j grows with it): matches jnp.argmin ties
      if (s0 < bv[q]) { bv[q] = s0; bi[q] = j0; }
      if (s1 < bv[q]) { bv[q] = s1; bi[q] = j1; }
    }
  }

  // Cross-thread reduction: wave shuffle then tiny LDS combine.
  __shared__ float rv[4][QT];
  __shared__ int ri[4][QT];
  const int lane = t & 63, w = t >> 6;
#pragma unroll
  for (int q = 0; q < QT; ++q) {
    float v = bv[q];
    int ix = bi[q];
    for (int off = 32; off; off >>= 1) {
      const float ov = __shfl_down(v, off);
      const int oi = __shfl_down(ix, off);
      if (ov < v || (ov == v && oi < ix)) { v = ov; ix = oi; }
    }
    if (lane == 0) { rv[w][q] = v; ri[w][q] = ix; }
  }
  __syncthreads();
  if (t < QT) {
    float v = rv[0][t];
    int ix = ri[0][t];
#pragma unroll
    for (int w2 = 1; w2 < 4; ++w2) {
      const float ov = rv[w2][t];
      const int oi = ri[w2][t];
      if (ov < v || (ov == v && oi < ix)) { v = ov; ix = oi; }
    }
    out[q0 + t] = lab[ix];
  }
}

extern "C" void kernel_launch(void* const* d_in, const int* in_sizes, int n_in,
                              void* d_out, int out_size, void* d_ws, size_t ws_size,
                              hipStream_t stream) {
  const float* x = (const float*)d_in[0];
  const float* y = (const float*)d_in[1];
  const float* lab = (const float*)d_in[2];
  float* out = (float*)d_out;

  if (ws_size >= (size_t)NM * sizeof(float)) {
    float* h = (float*)d_ws;
    h_kernel<<<NM / BT, BT, 0, stream>>>(y, h);
    nn_kernel<1><<<NQ / QT, BT, 0, stream>>>(x, y, lab, h, out);
  } else {
    nn_kernel<0><<<NQ / QT, BT, 0, stream>>>(x, y, lab, nullptr, out);
  }
}